// Round 13
// baseline (332.232 us; speedup 1.0000x reference)
//
#include <hip/hip_runtime.h>

typedef unsigned short u16;
typedef __attribute__((ext_vector_type(8))) short bf16x8;  // 8 bf16 (4 VGPRs)
typedef __attribute__((ext_vector_type(4))) float f32x4;   // MFMA C/D frag

__device__ __forceinline__ float bf2f(u16 x) {
  union { unsigned u; float f; } v; v.u = ((unsigned)x) << 16; return v.f;
}
__device__ __forceinline__ u16 f2bf(float f) {
  union { float f; unsigned u; } v; v.f = f;
  unsigned r = v.u + 0x7FFFu + ((v.u >> 16) & 1u);  // RNE
  return (u16)(r >> 16);
}
__device__ __forceinline__ float clampf(float v) {
  return fmaxf(fminf(v, 1.0e4f), -1.0e4f);
}
// async global->LDS, 16B per lane; LDS dest = wave-uniform base + lane*16
__device__ __forceinline__ void gll16(const u16* g, u16* l) {
  __builtin_amdgcn_global_load_lds(
      (const __attribute__((address_space(1))) void*)g,
      (__attribute__((address_space(3))) void*)l, 16, 0, 0);
}

// ---------- convert x (f32) -> bf16 ----------
__global__ __launch_bounds__(256) void convert_x(
    const float* __restrict__ x, u16* __restrict__ xbf) {
  const int i0 = (blockIdx.x * 256 + threadIdx.x) * 4;
  const float4 v = *(const float4*)(x + i0);
  xbf[i0 + 0] = f2bf(v.x); xbf[i0 + 1] = f2bf(v.y);
  xbf[i0 + 2] = f2bf(v.z); xbf[i0 + 3] = f2bf(v.w);
}

// ---------- transpose f32 in[R][C] -> bf16 out[C][R] ----------
__global__ __launch_bounds__(256) void transpose_f32_bf16(
    const float* __restrict__ in, u16* __restrict__ out, int R, int C) {
  __shared__ u16 tile[32][33];
  const int bc = blockIdx.x * 32, br = blockIdx.y * 32;
  const int tx = threadIdx.x & 31, ty = threadIdx.x >> 5;
  #pragma unroll
  for (int i = ty; i < 32; i += 8)
    tile[i][tx] = f2bf(in[(size_t)(br + i) * C + bc + tx]);
  __syncthreads();
  #pragma unroll
  for (int i = ty; i < 32; i += 8)
    out[(size_t)(bc + i) * R + br + tx] = tile[tx][i];
}

// ---------- GEMM1: QKV projection ----------
// R12 analysis: 805 MB of L2/L3 reads at ~7.7 TB/s => L3-BW-bound, so R13
// swaps grid axes: blockIdx.x = M-tile => XCD = m%8 (round-robin heuristic),
// all 24 blocks sharing an A-tile co-resident on one XCD (A/XCD = 2MB < L2).
__global__ __launch_bounds__(256) void gemm1_qkv(
    const u16* __restrict__ A, const u16* __restrict__ Bt,
    const float* __restrict__ bias, u16* __restrict__ qk,
    u16* __restrict__ vt, int K) {
  __shared__ u16 As[128 * 32];
  __shared__ u16 Bs[128 * 32];
  const int tid = threadIdx.x;
  const int m0 = blockIdx.x * 128, n0 = blockIdx.y * 128;  // x = M (XCD key)
  const int wave = tid >> 6, lane = tid & 63;
  const int quad = lane >> 4, l16 = lane & 15;
  const int wm = (wave >> 1) * 64, wn = (wave & 1) * 64;
  const int sr = (lane >> 2), sp = lane & 3;

  f32x4 acc[4][4] = {};
  const u16* gA = A + (size_t)(m0 + wave * 32 + sr) * K + sp * 8;
  const u16* gB = Bt + (size_t)(n0 + wave * 32 + sr) * K + sp * 8;

  for (int k0 = 0; k0 < K; k0 += 32) {
    #pragma unroll
    for (int t = 0; t < 2; ++t) {
      gll16(gA + (size_t)(t * 16) * K + k0, &As[(wave * 32 + t * 16) * 32]);
      gll16(gB + (size_t)(t * 16) * K + k0, &Bs[(wave * 32 + t * 16) * 32]);
    }
    __syncthreads();
    bf16x8 af[4], bfr[4];
    #pragma unroll
    for (int i = 0; i < 4; ++i)
      af[i] = *(const bf16x8*)&As[(wm + i * 16 + l16) * 32 + quad * 8];
    #pragma unroll
    for (int j = 0; j < 4; ++j)
      bfr[j] = *(const bf16x8*)&Bs[(wn + j * 16 + l16) * 32 + quad * 8];
    #pragma unroll
    for (int i = 0; i < 4; ++i)
      #pragma unroll
      for (int j = 0; j < 4; ++j)
        acc[i][j] = __builtin_amdgcn_mfma_f32_16x16x32_bf16(af[i], bfr[j], acc[i][j], 0, 0, 0);
    __syncthreads();
  }

  #pragma unroll
  for (int i = 0; i < 4; ++i) {
    const int row = m0 + wm + i * 16 + quad * 4;
    #pragma unroll
    for (int j = 0; j < 4; ++j) {
      const int col = n0 + wn + j * 16 + l16;
      const float bv = bias[col];
      if (col < 2048) {
        #pragma unroll
        for (int r = 0; r < 4; ++r)
          qk[(size_t)(row + r) * 2048 + col] = f2bf(clampf(acc[i][j][r] + bv));
      } else {
        const int d = col & 63;
        const int hh = (col - 2048) >> 6;
        #pragma unroll
        for (int r = 0; r < 4; ++r) {
          const int rr = row + r;
          const int bb = rr >> 11, ss = rr & 2047;
          vt[(size_t)(bb * 16 + hh) * 131072 + d * 2048 + ss] =
              f2bf(clampf(acc[i][j][r] + bv));
        }
      }
    }
  }
}

// ---------- GEMM2: out(f32) = ctx * w_proj^T + bias, same swizzle ----------
__global__ __launch_bounds__(256) void gemm2_proj(
    const u16* __restrict__ A, const u16* __restrict__ Bt,
    const float* __restrict__ bias, float* __restrict__ out, int K) {
  __shared__ u16 As[128 * 32];
  __shared__ u16 Bs[128 * 32];
  const int tid = threadIdx.x;
  const int m0 = blockIdx.x * 128, n0 = blockIdx.y * 128;  // x = M (XCD key)
  const int wave = tid >> 6, lane = tid & 63;
  const int quad = lane >> 4, l16 = lane & 15;
  const int wm = (wave >> 1) * 64, wn = (wave & 1) * 64;
  const int sr = (lane >> 2), sp = lane & 3;

  f32x4 acc[4][4] = {};
  const u16* gA = A + (size_t)(m0 + wave * 32 + sr) * K + sp * 8;
  const u16* gB = Bt + (size_t)(n0 + wave * 32 + sr) * K + sp * 8;

  for (int k0 = 0; k0 < K; k0 += 32) {
    #pragma unroll
    for (int t = 0; t < 2; ++t) {
      gll16(gA + (size_t)(t * 16) * K + k0, &As[(wave * 32 + t * 16) * 32]);
      gll16(gB + (size_t)(t * 16) * K + k0, &Bs[(wave * 32 + t * 16) * 32]);
    }
    __syncthreads();
    bf16x8 af[4], bfr[4];
    #pragma unroll
    for (int i = 0; i < 4; ++i)
      af[i] = *(const bf16x8*)&As[(wm + i * 16 + l16) * 32 + quad * 8];
    #pragma unroll
    for (int j = 0; j < 4; ++j)
      bfr[j] = *(const bf16x8*)&Bs[(wn + j * 16 + l16) * 32 + quad * 8];
    #pragma unroll
    for (int i = 0; i < 4; ++i)
      #pragma unroll
      for (int j = 0; j < 4; ++j)
        acc[i][j] = __builtin_amdgcn_mfma_f32_16x16x32_bf16(af[i], bfr[j], acc[i][j], 0, 0, 0);
    __syncthreads();
  }

  #pragma unroll
  for (int i = 0; i < 4; ++i) {
    const int row = m0 + wm + i * 16 + quad * 4;
    #pragma unroll
    for (int j = 0; j < 4; ++j) {
      const int col = n0 + wn + j * 16 + l16;
      const float bv = bias[col];
      #pragma unroll
      for (int r = 0; r < 4; ++r)
        out[(size_t)(row + r) * 1024 + col] = clampf(acc[i][j][r] + bv);
    }
  }
}

// ---------- fused flash attention, v5 (FROZEN from R11: 136 us) ----------
__global__ __launch_bounds__(256, 4) void attn_fused(
    const u16* __restrict__ qk, const u16* __restrict__ vt,
    u16* __restrict__ ctx) {
  __shared__ u16 Ks[64][72];
  __shared__ u16 Vs[64][72];
  __shared__ u16 Pl[4][32][72];
  const int bh = blockIdx.x, qt = blockIdx.y;
  const int b = bh >> 4, h = bh & 15;
  const int tid = threadIdx.x;
  const int w = tid >> 6, lane = tid & 63;
  const int quad = lane >> 4, l16 = lane & 15;
  const int qbase = qt * 128 + w * 32;

  const u16* qptr = qk + (size_t)(b * 2048) * 2048 + h * 64;
  bf16x8 qf[2][2];
  #pragma unroll
  for (int i = 0; i < 2; ++i)
    #pragma unroll
    for (int ks = 0; ks < 2; ++ks)
      qf[i][ks] = *(const bf16x8*)(qptr + (size_t)(qbase + i * 16 + l16) * 2048 + ks * 32 + quad * 8);

  const u16* kptr = qk + (size_t)(b * 2048) * 2048 + 1024 + h * 64;
  const u16* vptr = vt + (size_t)bh * 131072;

  const int srow = tid >> 3, scol = (tid & 7) * 8;

  f32x4 o[2][4] = {};
  f32x4 lsum[2] = {};
  const float c2 = 0.125f * 1.44269504088896340736f;

  bf16x8 k0 = *(const bf16x8*)(kptr + (size_t)srow * 2048 + scol);
  bf16x8 k1 = *(const bf16x8*)(kptr + (size_t)(srow + 32) * 2048 + scol);
  bf16x8 v0 = *(const bf16x8*)(vptr + (size_t)srow * 2048 + scol);
  bf16x8 v1 = *(const bf16x8*)(vptr + (size_t)(srow + 32) * 2048 + scol);

  for (int kv0 = 0; kv0 < 2048; kv0 += 64) {
    __syncthreads();
    *(bf16x8*)&Ks[srow][scol]      = k0;
    *(bf16x8*)&Ks[srow + 32][scol] = k1;
    *(bf16x8*)&Vs[srow][scol]      = v0;
    *(bf16x8*)&Vs[srow + 32][scol] = v1;
    __syncthreads();
    const int kvn = (kv0 + 64) & 2047;
    k0 = *(const bf16x8*)(kptr + (size_t)(kvn + srow) * 2048 + scol);
    k1 = *(const bf16x8*)(kptr + (size_t)(kvn + srow + 32) * 2048 + scol);
    v0 = *(const bf16x8*)(vptr + (size_t)srow * 2048 + kvn + scol);
    v1 = *(const bf16x8*)(vptr + (size_t)(srow + 32) * 2048 + kvn + scol);

    f32x4 s[2][4] = {};
    #pragma unroll
    for (int jj = 0; jj < 4; ++jj) {
      #pragma unroll
      for (int ks = 0; ks < 2; ++ks) {
        bf16x8 kf = *(const bf16x8*)&Ks[jj * 16 + l16][ks * 32 + quad * 8];
        #pragma unroll
        for (int i = 0; i < 2; ++i)
          s[i][jj] = __builtin_amdgcn_mfma_f32_16x16x32_bf16(qf[i][ks], kf, s[i][jj], 0, 0, 0);
      }
    }
    #pragma unroll
    for (int i = 0; i < 2; ++i)
      #pragma unroll
      for (int jj = 0; jj < 4; ++jj)
        #pragma unroll
        for (int r = 0; r < 4; ++r) {
          const float p = exp2f(s[i][jj][r] * c2);
          lsum[i][r] += p;
          union { float f; unsigned u; } vv; vv.f = p;
          Pl[w][i * 16 + quad * 4 + r][jj * 16 + l16] = (u16)((vv.u + 0x8000u) >> 16);
        }
    #pragma unroll
    for (int ks = 0; ks < 2; ++ks) {
      bf16x8 af0 = *(const bf16x8*)&Pl[w][l16][ks * 32 + quad * 8];
      bf16x8 af1 = *(const bf16x8*)&Pl[w][16 + l16][ks * 32 + quad * 8];
      #pragma unroll
      for (int j = 0; j < 4; ++j) {
        bf16x8 vf = *(const bf16x8*)&Vs[j * 16 + l16][ks * 32 + quad * 8];
        o[0][j] = __builtin_amdgcn_mfma_f32_16x16x32_bf16(af0, vf, o[0][j], 0, 0, 0);
        o[1][j] = __builtin_amdgcn_mfma_f32_16x16x32_bf16(af1, vf, o[1][j], 0, 0, 0);
      }
    }
  }

  #pragma unroll
  for (int i = 0; i < 2; ++i)
    #pragma unroll
    for (int r = 0; r < 4; ++r) {
      float lv = lsum[i][r];
      #pragma unroll
      for (int d = 1; d < 16; d <<= 1) lv += __shfl_xor(lv, d, 64);
      lsum[i][r] = lv;
    }
  u16* cbase = ctx + (size_t)(b * 2048) * 1024 + h * 64;
  #pragma unroll
  for (int i = 0; i < 2; ++i)
    #pragma unroll
    for (int r = 0; r < 4; ++r) {
      const float inv = 1.0f / lsum[i][r];
      const int q = qbase + i * 16 + quad * 4 + r;
      #pragma unroll
      for (int j = 0; j < 4; ++j)
        cbase[(size_t)q * 1024 + j * 16 + l16] = f2bf(o[i][j][r] * inv);
    }
}

extern "C" void kernel_launch(void* const* d_in, const int* in_sizes, int n_in,
                              void* d_out, int out_size, void* d_ws, size_t ws_size,
                              hipStream_t stream) {
  (void)out_size;
  const float *x = nullptr, *wq = nullptr, *bq = nullptr, *wp = nullptr, *bp = nullptr;
  for (int i = 0; i < n_in; ++i) {
    switch (in_sizes[i]) {
      case 8388608: x  = (const float*)d_in[i]; break;
      case 3145728: wq = (const float*)d_in[i]; break;
      case 3072:    bq = (const float*)d_in[i]; break;
      case 1048576: wp = (const float*)d_in[i]; break;
      case 1024:    bp = (const float*)d_in[i]; break;
      default: break;
    }
  }
  if (!x || !wq || !bq || !wp || !bp) {
    x  = (const float*)d_in[0]; wq = (const float*)d_in[1];
    bq = (const float*)d_in[2]; wp = (const float*)d_in[3];
    bp = (const float*)d_in[4];
  }
  float* out = (float*)d_out;

  const size_t NEED = 75497472;
  if (ws_size < NEED) return;

  char* ws = (char*)d_ws;
  u16* qkb = (u16*)(ws);              // [8192][2048] Q,K
  u16* vt  = (u16*)(ws + 33554432);   // [64][64][2048] V^T
  u16* xbf = (u16*)(ws + 50331648);   // x_bf, then ctx
  u16* wT1 = (u16*)(ws + 67108864);
  u16* wT2 = (u16*)(ws + 73400320);

  convert_x<<<8192, 256, 0, stream>>>(x, xbf);
  transpose_f32_bf16<<<dim3(96, 32), 256, 0, stream>>>(wq, wT1, 1024, 3072);
  transpose_f32_bf16<<<dim3(32, 32), 256, 0, stream>>>(wp, wT2, 1024, 1024);
  // grid: x = M-tiles (XCD locality key), y = N-tiles
  gemm1_qkv<<<dim3(64, 24), 256, 0, stream>>>(xbf, wT1, bq, qkb, vt, 1024);
  attn_fused<<<dim3(64, 16), 256, 0, stream>>>(qkb, vt, xbf /*ctx*/);
  gemm2_proj<<<dim3(64, 8), 256, 0, stream>>>(xbf /*ctx*/, wT2, bp, out, 1024);
}

// Round 14
// 300.732 us; speedup vs baseline: 1.1047x; 1.1047x over previous
//
#include <hip/hip_runtime.h>

typedef unsigned short u16;
typedef __attribute__((ext_vector_type(8))) short bf16x8;  // 8 bf16 (4 VGPRs)
typedef __attribute__((ext_vector_type(4))) float f32x4;   // MFMA C/D frag

__device__ __forceinline__ float bf2f(u16 x) {
  union { unsigned u; float f; } v; v.u = ((unsigned)x) << 16; return v.f;
}
__device__ __forceinline__ u16 f2bf(float f) {
  union { float f; unsigned u; } v; v.f = f;
  unsigned r = v.u + 0x7FFFu + ((v.u >> 16) & 1u);  // RNE
  return (u16)(r >> 16);
}
__device__ __forceinline__ float clampf(float v) {
  return fmaxf(fminf(v, 1.0e4f), -1.0e4f);
}
// async global->LDS, 16B per lane; LDS dest = wave-uniform base + lane*16
__device__ __forceinline__ void gll16(const u16* g, u16* l) {
  __builtin_amdgcn_global_load_lds(
      (const __attribute__((address_space(1))) void*)g,
      (__attribute__((address_space(3))) void*)l, 16, 0, 0);
}

// ---------- convert x (f32) -> bf16 ----------
__global__ __launch_bounds__(256) void convert_x(
    const float* __restrict__ x, u16* __restrict__ xbf) {
  const int i0 = (blockIdx.x * 256 + threadIdx.x) * 4;
  const float4 v = *(const float4*)(x + i0);
  xbf[i0 + 0] = f2bf(v.x); xbf[i0 + 1] = f2bf(v.y);
  xbf[i0 + 2] = f2bf(v.z); xbf[i0 + 3] = f2bf(v.w);
}

// ---------- transpose f32 in[R][C] -> bf16 out[C][R] ----------
__global__ __launch_bounds__(256) void transpose_f32_bf16(
    const float* __restrict__ in, u16* __restrict__ out, int R, int C) {
  __shared__ u16 tile[32][33];
  const int bc = blockIdx.x * 32, br = blockIdx.y * 32;
  const int tx = threadIdx.x & 31, ty = threadIdx.x >> 5;
  #pragma unroll
  for (int i = ty; i < 32; i += 8)
    tile[i][tx] = f2bf(in[(size_t)(br + i) * C + bc + tx]);
  __syncthreads();
  #pragma unroll
  for (int i = ty; i < 32; i += 8)
    out[(size_t)(bc + i) * R + br + tx] = tile[tx][i];
}

// ---------- GEMM1: QKV projection, BK=64 via dual 32-col LDS arrays ----------
// R13 analysis: K=1024 -> only 32 k-iters; barrier drain per iter is the
// suspected overhead (m102 shape curve). BK=64 halves barrier count. Two
// separate 32-col arrays per operand keep the 16-dw row stride (2-way-free
// banks) AND the global_load_lds contiguity rule (no padding allowed).
__global__ __launch_bounds__(256) void gemm1_qkv(
    const u16* __restrict__ A, const u16* __restrict__ Bt,
    const float* __restrict__ bias, u16* __restrict__ qk,
    u16* __restrict__ vt, int K) {
  __shared__ u16 As0[128 * 32], As1[128 * 32];
  __shared__ u16 Bs0[128 * 32], Bs1[128 * 32];
  const int tid = threadIdx.x;
  const int m0 = blockIdx.x * 128, n0 = blockIdx.y * 128;  // x = M (XCD key)
  const int wave = tid >> 6, lane = tid & 63;
  const int quad = lane >> 4, l16 = lane & 15;
  const int wm = (wave >> 1) * 64, wn = (wave & 1) * 64;
  const int sr = (lane >> 2), sp = lane & 3;  // staging row-in-16 / 16B part

  f32x4 acc[4][4] = {};
  const u16* gA = A + (size_t)(m0 + wave * 32 + sr) * K + sp * 8;
  const u16* gB = Bt + (size_t)(n0 + wave * 32 + sr) * K + sp * 8;

  for (int k0 = 0; k0 < K; k0 += 64) {
    #pragma unroll
    for (int t = 0; t < 2; ++t) {
      gll16(gA + (size_t)(t * 16) * K + k0,      &As0[(wave * 32 + t * 16) * 32]);
      gll16(gA + (size_t)(t * 16) * K + k0 + 32, &As1[(wave * 32 + t * 16) * 32]);
      gll16(gB + (size_t)(t * 16) * K + k0,      &Bs0[(wave * 32 + t * 16) * 32]);
      gll16(gB + (size_t)(t * 16) * K + k0 + 32, &Bs1[(wave * 32 + t * 16) * 32]);
    }
    __syncthreads();
    #pragma unroll
    for (int ks = 0; ks < 2; ++ks) {
      const u16* Ah = ks ? As1 : As0;
      const u16* Bh = ks ? Bs1 : Bs0;
      bf16x8 af[4], bfr[4];
      #pragma unroll
      for (int i = 0; i < 4; ++i)
        af[i] = *(const bf16x8*)&Ah[(wm + i * 16 + l16) * 32 + quad * 8];
      #pragma unroll
      for (int j = 0; j < 4; ++j)
        bfr[j] = *(const bf16x8*)&Bh[(wn + j * 16 + l16) * 32 + quad * 8];
      #pragma unroll
      for (int i = 0; i < 4; ++i)
        #pragma unroll
        for (int j = 0; j < 4; ++j)
          acc[i][j] = __builtin_amdgcn_mfma_f32_16x16x32_bf16(af[i], bfr[j], acc[i][j], 0, 0, 0);
    }
    __syncthreads();
  }

  #pragma unroll
  for (int i = 0; i < 4; ++i) {
    const int row = m0 + wm + i * 16 + quad * 4;
    #pragma unroll
    for (int j = 0; j < 4; ++j) {
      const int col = n0 + wn + j * 16 + l16;
      const float bv = bias[col];
      if (col < 2048) {
        #pragma unroll
        for (int r = 0; r < 4; ++r)
          qk[(size_t)(row + r) * 2048 + col] = f2bf(clampf(acc[i][j][r] + bv));
      } else {
        const int d = col & 63;
        const int hh = (col - 2048) >> 6;
        #pragma unroll
        for (int r = 0; r < 4; ++r) {
          const int rr = row + r;
          const int bb = rr >> 11, ss = rr & 2047;
          vt[(size_t)(bb * 16 + hh) * 131072 + d * 2048 + ss] =
              f2bf(clampf(acc[i][j][r] + bv));
        }
      }
    }
  }
}

// ---------- GEMM2: out(f32) = ctx * w_proj^T + bias, BK=64 same scheme ----------
__global__ __launch_bounds__(256) void gemm2_proj(
    const u16* __restrict__ A, const u16* __restrict__ Bt,
    const float* __restrict__ bias, float* __restrict__ out, int K) {
  __shared__ u16 As0[128 * 32], As1[128 * 32];
  __shared__ u16 Bs0[128 * 32], Bs1[128 * 32];
  const int tid = threadIdx.x;
  const int m0 = blockIdx.x * 128, n0 = blockIdx.y * 128;
  const int wave = tid >> 6, lane = tid & 63;
  const int quad = lane >> 4, l16 = lane & 15;
  const int wm = (wave >> 1) * 64, wn = (wave & 1) * 64;
  const int sr = (lane >> 2), sp = lane & 3;

  f32x4 acc[4][4] = {};
  const u16* gA = A + (size_t)(m0 + wave * 32 + sr) * K + sp * 8;
  const u16* gB = Bt + (size_t)(n0 + wave * 32 + sr) * K + sp * 8;

  for (int k0 = 0; k0 < K; k0 += 64) {
    #pragma unroll
    for (int t = 0; t < 2; ++t) {
      gll16(gA + (size_t)(t * 16) * K + k0,      &As0[(wave * 32 + t * 16) * 32]);
      gll16(gA + (size_t)(t * 16) * K + k0 + 32, &As1[(wave * 32 + t * 16) * 32]);
      gll16(gB + (size_t)(t * 16) * K + k0,      &Bs0[(wave * 32 + t * 16) * 32]);
      gll16(gB + (size_t)(t * 16) * K + k0 + 32, &Bs1[(wave * 32 + t * 16) * 32]);
    }
    __syncthreads();
    #pragma unroll
    for (int ks = 0; ks < 2; ++ks) {
      const u16* Ah = ks ? As1 : As0;
      const u16* Bh = ks ? Bs1 : Bs0;
      bf16x8 af[4], bfr[4];
      #pragma unroll
      for (int i = 0; i < 4; ++i)
        af[i] = *(const bf16x8*)&Ah[(wm + i * 16 + l16) * 32 + quad * 8];
      #pragma unroll
      for (int j = 0; j < 4; ++j)
        bfr[j] = *(const bf16x8*)&Bh[(wn + j * 16 + l16) * 32 + quad * 8];
      #pragma unroll
      for (int i = 0; i < 4; ++i)
        #pragma unroll
        for (int j = 0; j < 4; ++j)
          acc[i][j] = __builtin_amdgcn_mfma_f32_16x16x32_bf16(af[i], bfr[j], acc[i][j], 0, 0, 0);
    }
    __syncthreads();
  }

  #pragma unroll
  for (int i = 0; i < 4; ++i) {
    const int row = m0 + wm + i * 16 + quad * 4;
    #pragma unroll
    for (int j = 0; j < 4; ++j) {
      const int col = n0 + wn + j * 16 + l16;
      const float bv = bias[col];
      #pragma unroll
      for (int r = 0; r < 4; ++r)
        out[(size_t)(row + r) * 1024 + col] = clampf(acc[i][j][r] + bv);
    }
  }
}

// ---------- fused flash attention, v6 ----------
// v5 + MFMA row-sum for l: B-operand = ones reuses the PV A-frags, so the 32
// per-lane lsum adds AND the epilogue shfl reduction vanish (VALU was the
// busiest pipe at 61%; matrix pipe at 22% absorbs 4 extra mfma/iter). C-layout
// of lacc: every lane's lacc[i][r] holds the complete row sum already.
__global__ __launch_bounds__(256, 4) void attn_fused(
    const u16* __restrict__ qk, const u16* __restrict__ vt,
    u16* __restrict__ ctx) {
  __shared__ u16 Ks[64][72];
  __shared__ u16 Vs[64][72];
  __shared__ u16 Pl[4][32][72];
  const int bh = blockIdx.x, qt = blockIdx.y;
  const int b = bh >> 4, h = bh & 15;
  const int tid = threadIdx.x;
  const int w = tid >> 6, lane = tid & 63;
  const int quad = lane >> 4, l16 = lane & 15;
  const int qbase = qt * 128 + w * 32;

  const u16* qptr = qk + (size_t)(b * 2048) * 2048 + h * 64;
  bf16x8 qf[2][2];
  #pragma unroll
  for (int i = 0; i < 2; ++i)
    #pragma unroll
    for (int ks = 0; ks < 2; ++ks)
      qf[i][ks] = *(const bf16x8*)(qptr + (size_t)(qbase + i * 16 + l16) * 2048 + ks * 32 + quad * 8);

  const u16* kptr = qk + (size_t)(b * 2048) * 2048 + 1024 + h * 64;
  const u16* vptr = vt + (size_t)bh * 131072;

  const int srow = tid >> 3, scol = (tid & 7) * 8;

  f32x4 o[2][4] = {};
  f32x4 lacc[2] = {};  // MFMA row-sum accumulator (all 16 cols identical)
  const short one = (short)0x3F80;  // bf16 1.0
  const bf16x8 ones = {one, one, one, one, one, one, one, one};
  const float c2 = 0.125f * 1.44269504088896340736f;

  bf16x8 k0 = *(const bf16x8*)(kptr + (size_t)srow * 2048 + scol);
  bf16x8 k1 = *(const bf16x8*)(kptr + (size_t)(srow + 32) * 2048 + scol);
  bf16x8 v0 = *(const bf16x8*)(vptr + (size_t)srow * 2048 + scol);
  bf16x8 v1 = *(const bf16x8*)(vptr + (size_t)(srow + 32) * 2048 + scol);

  for (int kv0 = 0; kv0 < 2048; kv0 += 64) {
    __syncthreads();
    *(bf16x8*)&Ks[srow][scol]      = k0;
    *(bf16x8*)&Ks[srow + 32][scol] = k1;
    *(bf16x8*)&Vs[srow][scol]      = v0;
    *(bf16x8*)&Vs[srow + 32][scol] = v1;
    __syncthreads();
    const int kvn = (kv0 + 64) & 2047;
    k0 = *(const bf16x8*)(kptr + (size_t)(kvn + srow) * 2048 + scol);
    k1 = *(const bf16x8*)(kptr + (size_t)(kvn + srow + 32) * 2048 + scol);
    v0 = *(const bf16x8*)(vptr + (size_t)srow * 2048 + kvn + scol);
    v1 = *(const bf16x8*)(vptr + (size_t)(srow + 32) * 2048 + kvn + scol);

    f32x4 s[2][4] = {};
    #pragma unroll
    for (int jj = 0; jj < 4; ++jj) {
      #pragma unroll
      for (int ks = 0; ks < 2; ++ks) {
        bf16x8 kf = *(const bf16x8*)&Ks[jj * 16 + l16][ks * 32 + quad * 8];
        #pragma unroll
        for (int i = 0; i < 2; ++i)
          s[i][jj] = __builtin_amdgcn_mfma_f32_16x16x32_bf16(qf[i][ks], kf, s[i][jj], 0, 0, 0);
      }
    }
    #pragma unroll
    for (int i = 0; i < 2; ++i)
      #pragma unroll
      for (int jj = 0; jj < 4; ++jj)
        #pragma unroll
        for (int r = 0; r < 4; ++r) {
          const float p = exp2f(s[i][jj][r] * c2);
          union { float f; unsigned u; } vv; vv.f = p;
          Pl[w][i * 16 + quad * 4 + r][jj * 16 + l16] = (u16)((vv.u + 0x8000u) >> 16);
        }
    #pragma unroll
    for (int ks = 0; ks < 2; ++ks) {
      bf16x8 af0 = *(const bf16x8*)&Pl[w][l16][ks * 32 + quad * 8];
      bf16x8 af1 = *(const bf16x8*)&Pl[w][16 + l16][ks * 32 + quad * 8];
      lacc[0] = __builtin_amdgcn_mfma_f32_16x16x32_bf16(af0, ones, lacc[0], 0, 0, 0);
      lacc[1] = __builtin_amdgcn_mfma_f32_16x16x32_bf16(af1, ones, lacc[1], 0, 0, 0);
      #pragma unroll
      for (int j = 0; j < 4; ++j) {
        bf16x8 vf = *(const bf16x8*)&Vs[j * 16 + l16][ks * 32 + quad * 8];
        o[0][j] = __builtin_amdgcn_mfma_f32_16x16x32_bf16(af0, vf, o[0][j], 0, 0, 0);
        o[1][j] = __builtin_amdgcn_mfma_f32_16x16x32_bf16(af1, vf, o[1][j], 0, 0, 0);
      }
    }
  }

  // epilogue: lacc[i][r] is already the complete row sum in every lane
  u16* cbase = ctx + (size_t)(b * 2048) * 1024 + h * 64;
  #pragma unroll
  for (int i = 0; i < 2; ++i)
    #pragma unroll
    for (int r = 0; r < 4; ++r) {
      const float inv = 1.0f / lacc[i][r];
      const int q = qbase + i * 16 + quad * 4 + r;
      #pragma unroll
      for (int j = 0; j < 4; ++j)
        cbase[(size_t)q * 1024 + j * 16 + l16] = f2bf(o[i][j][r] * inv);
    }
}

extern "C" void kernel_launch(void* const* d_in, const int* in_sizes, int n_in,
                              void* d_out, int out_size, void* d_ws, size_t ws_size,
                              hipStream_t stream) {
  (void)out_size;
  const float *x = nullptr, *wq = nullptr, *bq = nullptr, *wp = nullptr, *bp = nullptr;
  for (int i = 0; i < n_in; ++i) {
    switch (in_sizes[i]) {
      case 8388608: x  = (const float*)d_in[i]; break;
      case 3145728: wq = (const float*)d_in[i]; break;
      case 3072:    bq = (const float*)d_in[i]; break;
      case 1048576: wp = (const float*)d_in[i]; break;
      case 1024:    bp = (const float*)d_in[i]; break;
      default: break;
    }
  }
  if (!x || !wq || !bq || !wp || !bp) {
    x  = (const float*)d_in[0]; wq = (const float*)d_in[1];
    bq = (const float*)d_in[2]; wp = (const float*)d_in[3];
    bp = (const float*)d_in[4];
  }
  float* out = (float*)d_out;

  const size_t NEED = 75497472;
  if (ws_size < NEED) return;

  char* ws = (char*)d_ws;
  u16* qkb = (u16*)(ws);              // [8192][2048] Q,K
  u16* vt  = (u16*)(ws + 33554432);   // [64][64][2048] V^T
  u16* xbf = (u16*)(ws + 50331648);   // x_bf, then ctx
  u16* wT1 = (u16*)(ws + 67108864);
  u16* wT2 = (u16*)(ws + 73400320);

  convert_x<<<8192, 256, 0, stream>>>(x, xbf);
  transpose_f32_bf16<<<dim3(96, 32), 256, 0, stream>>>(wq, wT1, 1024, 3072);
  transpose_f32_bf16<<<dim3(32, 32), 256, 0, stream>>>(wp, wT2, 1024, 1024);
  gemm1_qkv<<<dim3(64, 24), 256, 0, stream>>>(xbf, wT1, bq, qkb, vt, 1024);
  attn_fused<<<dim3(64, 16), 256, 0, stream>>>(qkb, vt, xbf /*ctx*/);
  gemm2_proj<<<dim3(64, 8), 256, 0, stream>>>(xbf /*ctx*/, wT2, bp, out, 1024);
}

// Round 15
// 298.749 us; speedup vs baseline: 1.1121x; 1.0066x over previous
//
#include <hip/hip_runtime.h>

typedef unsigned short u16;
typedef __attribute__((ext_vector_type(8))) short bf16x8;  // 8 bf16 (4 VGPRs)
typedef __attribute__((ext_vector_type(4))) float f32x4;   // MFMA C/D frag

__device__ __forceinline__ float bf2f(u16 x) {
  union { unsigned u; float f; } v; v.u = ((unsigned)x) << 16; return v.f;
}
__device__ __forceinline__ u16 f2bf(float f) {
  union { float f; unsigned u; } v; v.f = f;
  unsigned r = v.u + 0x7FFFu + ((v.u >> 16) & 1u);  // RNE
  return (u16)(r >> 16);
}
__device__ __forceinline__ float clampf(float v) {
  return fmaxf(fminf(v, 1.0e4f), -1.0e4f);
}
// async global->LDS, 16B per lane; LDS dest = wave-uniform base + lane*16
__device__ __forceinline__ void gll16(const u16* g, u16* l) {
  __builtin_amdgcn_global_load_lds(
      (const __attribute__((address_space(1))) void*)g,
      (__attribute__((address_space(3))) void*)l, 16, 0, 0);
}

// ---------- convert x (f32) -> bf16 ----------
__global__ __launch_bounds__(256) void convert_x(
    const float* __restrict__ x, u16* __restrict__ xbf) {
  const int i0 = (blockIdx.x * 256 + threadIdx.x) * 4;
  const float4 v = *(const float4*)(x + i0);
  xbf[i0 + 0] = f2bf(v.x); xbf[i0 + 1] = f2bf(v.y);
  xbf[i0 + 2] = f2bf(v.z); xbf[i0 + 3] = f2bf(v.w);
}

// ---------- transpose f32 in[R][C] -> bf16 out[C][R] ----------
__global__ __launch_bounds__(256) void transpose_f32_bf16(
    const float* __restrict__ in, u16* __restrict__ out, int R, int C) {
  __shared__ u16 tile[32][33];
  const int bc = blockIdx.x * 32, br = blockIdx.y * 32;
  const int tx = threadIdx.x & 31, ty = threadIdx.x >> 5;
  #pragma unroll
  for (int i = ty; i < 32; i += 8)
    tile[i][tx] = f2bf(in[(size_t)(br + i) * C + bc + tx]);
  __syncthreads();
  #pragma unroll
  for (int i = ty; i < 32; i += 8)
    out[(size_t)(bc + i) * R + br + tx] = tile[tx][i];
}

// ---------- GEMM1: QKV projection, BK=64 dual 32-col LDS (FROZEN R14) ----------
__global__ __launch_bounds__(256) void gemm1_qkv(
    const u16* __restrict__ A, const u16* __restrict__ Bt,
    const float* __restrict__ bias, u16* __restrict__ qk,
    u16* __restrict__ vt, int K) {
  __shared__ u16 As0[128 * 32], As1[128 * 32];
  __shared__ u16 Bs0[128 * 32], Bs1[128 * 32];
  const int tid = threadIdx.x;
  const int m0 = blockIdx.x * 128, n0 = blockIdx.y * 128;
  const int wave = tid >> 6, lane = tid & 63;
  const int quad = lane >> 4, l16 = lane & 15;
  const int wm = (wave >> 1) * 64, wn = (wave & 1) * 64;
  const int sr = (lane >> 2), sp = lane & 3;

  f32x4 acc[4][4] = {};
  const u16* gA = A + (size_t)(m0 + wave * 32 + sr) * K + sp * 8;
  const u16* gB = Bt + (size_t)(n0 + wave * 32 + sr) * K + sp * 8;

  for (int k0 = 0; k0 < K; k0 += 64) {
    #pragma unroll
    for (int t = 0; t < 2; ++t) {
      gll16(gA + (size_t)(t * 16) * K + k0,      &As0[(wave * 32 + t * 16) * 32]);
      gll16(gA + (size_t)(t * 16) * K + k0 + 32, &As1[(wave * 32 + t * 16) * 32]);
      gll16(gB + (size_t)(t * 16) * K + k0,      &Bs0[(wave * 32 + t * 16) * 32]);
      gll16(gB + (size_t)(t * 16) * K + k0 + 32, &Bs1[(wave * 32 + t * 16) * 32]);
    }
    __syncthreads();
    #pragma unroll
    for (int ks = 0; ks < 2; ++ks) {
      const u16* Ah = ks ? As1 : As0;
      const u16* Bh = ks ? Bs1 : Bs0;
      bf16x8 af[4], bfr[4];
      #pragma unroll
      for (int i = 0; i < 4; ++i)
        af[i] = *(const bf16x8*)&Ah[(wm + i * 16 + l16) * 32 + quad * 8];
      #pragma unroll
      for (int j = 0; j < 4; ++j)
        bfr[j] = *(const bf16x8*)&Bh[(wn + j * 16 + l16) * 32 + quad * 8];
      #pragma unroll
      for (int i = 0; i < 4; ++i)
        #pragma unroll
        for (int j = 0; j < 4; ++j)
          acc[i][j] = __builtin_amdgcn_mfma_f32_16x16x32_bf16(af[i], bfr[j], acc[i][j], 0, 0, 0);
    }
    __syncthreads();
  }

  #pragma unroll
  for (int i = 0; i < 4; ++i) {
    const int row = m0 + wm + i * 16 + quad * 4;
    #pragma unroll
    for (int j = 0; j < 4; ++j) {
      const int col = n0 + wn + j * 16 + l16;
      const float bv = bias[col];
      if (col < 2048) {
        #pragma unroll
        for (int r = 0; r < 4; ++r)
          qk[(size_t)(row + r) * 2048 + col] = f2bf(clampf(acc[i][j][r] + bv));
      } else {
        const int d = col & 63;
        const int hh = (col - 2048) >> 6;
        #pragma unroll
        for (int r = 0; r < 4; ++r) {
          const int rr = row + r;
          const int bb = rr >> 11, ss = rr & 2047;
          vt[(size_t)(bb * 16 + hh) * 131072 + d * 2048 + ss] =
              f2bf(clampf(acc[i][j][r] + bv));
        }
      }
    }
  }
}

// ---------- GEMM2: out(f32) = ctx * w_proj^T + bias (FROZEN R14) ----------
__global__ __launch_bounds__(256) void gemm2_proj(
    const u16* __restrict__ A, const u16* __restrict__ Bt,
    const float* __restrict__ bias, float* __restrict__ out, int K) {
  __shared__ u16 As0[128 * 32], As1[128 * 32];
  __shared__ u16 Bs0[128 * 32], Bs1[128 * 32];
  const int tid = threadIdx.x;
  const int m0 = blockIdx.x * 128, n0 = blockIdx.y * 128;
  const int wave = tid >> 6, lane = tid & 63;
  const int quad = lane >> 4, l16 = lane & 15;
  const int wm = (wave >> 1) * 64, wn = (wave & 1) * 64;
  const int sr = (lane >> 2), sp = lane & 3;

  f32x4 acc[4][4] = {};
  const u16* gA = A + (size_t)(m0 + wave * 32 + sr) * K + sp * 8;
  const u16* gB = Bt + (size_t)(n0 + wave * 32 + sr) * K + sp * 8;

  for (int k0 = 0; k0 < K; k0 += 64) {
    #pragma unroll
    for (int t = 0; t < 2; ++t) {
      gll16(gA + (size_t)(t * 16) * K + k0,      &As0[(wave * 32 + t * 16) * 32]);
      gll16(gA + (size_t)(t * 16) * K + k0 + 32, &As1[(wave * 32 + t * 16) * 32]);
      gll16(gB + (size_t)(t * 16) * K + k0,      &Bs0[(wave * 32 + t * 16) * 32]);
      gll16(gB + (size_t)(t * 16) * K + k0 + 32, &Bs1[(wave * 32 + t * 16) * 32]);
    }
    __syncthreads();
    #pragma unroll
    for (int ks = 0; ks < 2; ++ks) {
      const u16* Ah = ks ? As1 : As0;
      const u16* Bh = ks ? Bs1 : Bs0;
      bf16x8 af[4], bfr[4];
      #pragma unroll
      for (int i = 0; i < 4; ++i)
        af[i] = *(const bf16x8*)&Ah[(wm + i * 16 + l16) * 32 + quad * 8];
      #pragma unroll
      for (int j = 0; j < 4; ++j)
        bfr[j] = *(const bf16x8*)&Bh[(wn + j * 16 + l16) * 32 + quad * 8];
      #pragma unroll
      for (int i = 0; i < 4; ++i)
        #pragma unroll
        for (int j = 0; j < 4; ++j)
          acc[i][j] = __builtin_amdgcn_mfma_f32_16x16x32_bf16(af[i], bfr[j], acc[i][j], 0, 0, 0);
    }
    __syncthreads();
  }

  #pragma unroll
  for (int i = 0; i < 4; ++i) {
    const int row = m0 + wm + i * 16 + quad * 4;
    #pragma unroll
    for (int j = 0; j < 4; ++j) {
      const int col = n0 + wn + j * 16 + l16;
      const float bv = bias[col];
      #pragma unroll
      for (int r = 0; r < 4; ++r)
        out[(size_t)(row + r) * 1024 + col] = clampf(acc[i][j][r] + bv);
    }
  }
}

// ---------- fused flash attention, v7 ----------
// v6 + raw v_exp_f32: exp2f without fast-math lowers to ocml exp2 with
// range-fixup (~5-7 extra VALU/call). Args are bounded (|c2*s|<~15), so
// __builtin_amdgcn_exp2f (bare v_exp_f32) is exact-equivalent here and cuts
// the dominant VALU block (VALUBusy 60% with softmax-math floor ~25us).
__global__ __launch_bounds__(256, 4) void attn_fused(
    const u16* __restrict__ qk, const u16* __restrict__ vt,
    u16* __restrict__ ctx) {
  __shared__ u16 Ks[64][72];
  __shared__ u16 Vs[64][72];
  __shared__ u16 Pl[4][32][72];
  const int bh = blockIdx.x, qt = blockIdx.y;
  const int b = bh >> 4, h = bh & 15;
  const int tid = threadIdx.x;
  const int w = tid >> 6, lane = tid & 63;
  const int quad = lane >> 4, l16 = lane & 15;
  const int qbase = qt * 128 + w * 32;

  const u16* qptr = qk + (size_t)(b * 2048) * 2048 + h * 64;
  bf16x8 qf[2][2];
  #pragma unroll
  for (int i = 0; i < 2; ++i)
    #pragma unroll
    for (int ks = 0; ks < 2; ++ks)
      qf[i][ks] = *(const bf16x8*)(qptr + (size_t)(qbase + i * 16 + l16) * 2048 + ks * 32 + quad * 8);

  const u16* kptr = qk + (size_t)(b * 2048) * 2048 + 1024 + h * 64;
  const u16* vptr = vt + (size_t)bh * 131072;

  const int srow = tid >> 3, scol = (tid & 7) * 8;

  f32x4 o[2][4] = {};
  f32x4 lacc[2] = {};
  const short one = (short)0x3F80;  // bf16 1.0
  const bf16x8 ones = {one, one, one, one, one, one, one, one};
  const float c2 = 0.125f * 1.44269504088896340736f;

  bf16x8 k0 = *(const bf16x8*)(kptr + (size_t)srow * 2048 + scol);
  bf16x8 k1 = *(const bf16x8*)(kptr + (size_t)(srow + 32) * 2048 + scol);
  bf16x8 v0 = *(const bf16x8*)(vptr + (size_t)srow * 2048 + scol);
  bf16x8 v1 = *(const bf16x8*)(vptr + (size_t)(srow + 32) * 2048 + scol);

  for (int kv0 = 0; kv0 < 2048; kv0 += 64) {
    __syncthreads();
    *(bf16x8*)&Ks[srow][scol]      = k0;
    *(bf16x8*)&Ks[srow + 32][scol] = k1;
    *(bf16x8*)&Vs[srow][scol]      = v0;
    *(bf16x8*)&Vs[srow + 32][scol] = v1;
    __syncthreads();
    const int kvn = (kv0 + 64) & 2047;
    k0 = *(const bf16x8*)(kptr + (size_t)(kvn + srow) * 2048 + scol);
    k1 = *(const bf16x8*)(kptr + (size_t)(kvn + srow + 32) * 2048 + scol);
    v0 = *(const bf16x8*)(vptr + (size_t)srow * 2048 + kvn + scol);
    v1 = *(const bf16x8*)(vptr + (size_t)(srow + 32) * 2048 + kvn + scol);

    f32x4 s[2][4] = {};
    #pragma unroll
    for (int jj = 0; jj < 4; ++jj) {
      #pragma unroll
      for (int ks = 0; ks < 2; ++ks) {
        bf16x8 kf = *(const bf16x8*)&Ks[jj * 16 + l16][ks * 32 + quad * 8];
        #pragma unroll
        for (int i = 0; i < 2; ++i)
          s[i][jj] = __builtin_amdgcn_mfma_f32_16x16x32_bf16(qf[i][ks], kf, s[i][jj], 0, 0, 0);
      }
    }
    #pragma unroll
    for (int i = 0; i < 2; ++i)
      #pragma unroll
      for (int jj = 0; jj < 4; ++jj)
        #pragma unroll
        for (int r = 0; r < 4; ++r) {
          const float p = __builtin_amdgcn_exp2f(s[i][jj][r] * c2);  // bare v_exp_f32
          union { float f; unsigned u; } vv; vv.f = p;
          Pl[w][i * 16 + quad * 4 + r][jj * 16 + l16] = (u16)((vv.u + 0x8000u) >> 16);
        }
    #pragma unroll
    for (int ks = 0; ks < 2; ++ks) {
      bf16x8 af0 = *(const bf16x8*)&Pl[w][l16][ks * 32 + quad * 8];
      bf16x8 af1 = *(const bf16x8*)&Pl[w][16 + l16][ks * 32 + quad * 8];
      lacc[0] = __builtin_amdgcn_mfma_f32_16x16x32_bf16(af0, ones, lacc[0], 0, 0, 0);
      lacc[1] = __builtin_amdgcn_mfma_f32_16x16x32_bf16(af1, ones, lacc[1], 0, 0, 0);
      #pragma unroll
      for (int j = 0; j < 4; ++j) {
        bf16x8 vf = *(const bf16x8*)&Vs[j * 16 + l16][ks * 32 + quad * 8];
        o[0][j] = __builtin_amdgcn_mfma_f32_16x16x32_bf16(af0, vf, o[0][j], 0, 0, 0);
        o[1][j] = __builtin_amdgcn_mfma_f32_16x16x32_bf16(af1, vf, o[1][j], 0, 0, 0);
      }
    }
  }

  u16* cbase = ctx + (size_t)(b * 2048) * 1024 + h * 64;
  #pragma unroll
  for (int i = 0; i < 2; ++i)
    #pragma unroll
    for (int r = 0; r < 4; ++r) {
      const float inv = 1.0f / lacc[i][r];
      const int q = qbase + i * 16 + quad * 4 + r;
      #pragma unroll
      for (int j = 0; j < 4; ++j)
        cbase[(size_t)q * 1024 + j * 16 + l16] = f2bf(o[i][j][r] * inv);
    }
}

extern "C" void kernel_launch(void* const* d_in, const int* in_sizes, int n_in,
                              void* d_out, int out_size, void* d_ws, size_t ws_size,
                              hipStream_t stream) {
  (void)out_size;
  const float *x = nullptr, *wq = nullptr, *bq = nullptr, *wp = nullptr, *bp = nullptr;
  for (int i = 0; i < n_in; ++i) {
    switch (in_sizes[i]) {
      case 8388608: x  = (const float*)d_in[i]; break;
      case 3145728: wq = (const float*)d_in[i]; break;
      case 3072:    bq = (const float*)d_in[i]; break;
      case 1048576: wp = (const float*)d_in[i]; break;
      case 1024:    bp = (const float*)d_in[i]; break;
      default: break;
    }
  }
  if (!x || !wq || !bq || !wp || !bp) {
    x  = (const float*)d_in[0]; wq = (const float*)d_in[1];
    bq = (const float*)d_in[2]; wp = (const float*)d_in[3];
    bp = (const float*)d_in[4];
  }
  float* out = (float*)d_out;

  const size_t NEED = 75497472;
  if (ws_size < NEED) return;

  char* ws = (char*)d_ws;
  u16* qkb = (u16*)(ws);              // [8192][2048] Q,K
  u16* vt  = (u16*)(ws + 33554432);   // [64][64][2048] V^T
  u16* xbf = (u16*)(ws + 50331648);   // x_bf, then ctx
  u16* wT1 = (u16*)(ws + 67108864);
  u16* wT2 = (u16*)(ws + 73400320);

  convert_x<<<8192, 256, 0, stream>>>(x, xbf);
  transpose_f32_bf16<<<dim3(96, 32), 256, 0, stream>>>(wq, wT1, 1024, 3072);
  transpose_f32_bf16<<<dim3(32, 32), 256, 0, stream>>>(wp, wT2, 1024, 1024);
  gemm1_qkv<<<dim3(64, 24), 256, 0, stream>>>(xbf, wT1, bq, qkb, vt, 1024);
  attn_fused<<<dim3(64, 16), 256, 0, stream>>>(qkb, vt, xbf /*ctx*/);
  gemm2_proj<<<dim3(64, 8), 256, 0, stream>>>(xbf /*ctx*/, wT2, bp, out, 1024);
}